// Round 5
// baseline (405.489 us; speedup 1.0000x reference)
//
#include <hip/hip_runtime.h>

#define N_NODES 100000
#define F_IN 512
#define HID 16
#define F_OUT 40

#define NB 196        // buckets = row >> 9
#define BSHIFT 9
#define ROWS_PB 512
#define BCAP 17408    // mean 16384 + 8 sigma
#define CUR_PAD 16    // gcursor stride in ints (64B: one counter per line)

// ---------------- zero gcursor ----------------
__global__ void k_zero(int* __restrict__ g) {
    int i = blockIdx.x * 256 + threadIdx.x;
    if (i < NB * CUR_PAD) g[i] = 0;
}

// ---------------- pass 1: bucket scatter (packed u32) ----------------
__global__ __launch_bounds__(256) void k_part1(const int* __restrict__ ei, int E,
                                               int* __restrict__ gcursor,
                                               unsigned int* __restrict__ sortbuf) {
    __shared__ int cnt[NB];
    __shared__ int gb[NB];
    int t = threadIdx.x;
    int epb = (E + gridDim.x - 1) / gridDim.x;
    int base = blockIdx.x * epb;
    int lim = min(base + epb, E);
    for (int cbase = base; cbase < lim; cbase += 4096) {
        int cend = min(cbase + 4096, lim);
        for (int i = t; i < NB; i += 256) cnt[i] = 0;
        __syncthreads();
        unsigned int v[16];
        int bkt[16], mi[16];
#pragma unroll
        for (int i = 0; i < 16; ++i) {
            int e = cbase + i * 256 + t;
            bkt[i] = -1;
            if (e < cend) {
                int r = ei[e], c = ei[E + e];
                bkt[i] = r >> BSHIFT;
                v[i] = ((unsigned)(r & (ROWS_PB - 1)) << 17) | (unsigned)c;
                mi[i] = atomicAdd(&cnt[bkt[i]], 1);
            }
        }
        __syncthreads();
        for (int i = t; i < NB; i += 256)
            gb[i] = atomicAdd(&gcursor[i * CUR_PAD], cnt[i]);
        __syncthreads();
#pragma unroll
        for (int i = 0; i < 16; ++i)
            if (bkt[i] >= 0) {
                int idx = gb[bkt[i]] + mi[i];
                if (idx < BCAP) sortbuf[(size_t)bkt[i] * BCAP + idx] = v[i];
            }
        __syncthreads();
    }
}

// ---------------- bucket scan (single block) ----------------
__global__ __launch_bounds__(256) void k_bscan(const int* __restrict__ gcursor,
                                               int* __restrict__ bucketBase,
                                               int* __restrict__ rowptr) {
    __shared__ int s[256];
    int t = threadIdx.x;
    int v = (t < NB) ? min(gcursor[t * CUR_PAD], BCAP) : 0;
    s[t] = v;
    __syncthreads();
    for (int off = 1; off < 256; off <<= 1) {
        int a = (t >= off) ? s[t - off] : 0;
        __syncthreads();
        s[t] += a;
        __syncthreads();
    }
    if (t < NB) bucketBase[t] = s[t] - v;
    if (t == NB - 1) { bucketBase[NB] = s[t]; rowptr[N_NODES] = s[t]; }
}

// ---------------- pass 2: per-bucket CSR build ----------------
__global__ __launch_bounds__(256) void k_build(const unsigned int* __restrict__ sortbuf,
                                               const int* __restrict__ gcursor,
                                               const int* __restrict__ bucketBase,
                                               int* __restrict__ rowptr,
                                               float* __restrict__ dinv,
                                               int* __restrict__ colv) {
    __shared__ int cnt[ROWS_PB];
    __shared__ int rstart[ROWS_PB];
    __shared__ int s[256];
    int b = blockIdx.x, t = threadIdx.x;
    int n = min(gcursor[b * CUR_PAD], BCAP);
    const unsigned int* sb = sortbuf + (size_t)b * BCAP;
    int gbase = bucketBase[b];
    for (int i = t; i < ROWS_PB; i += 256) cnt[i] = 0;
    __syncthreads();
    for (int i = t; i < n; i += 256) atomicAdd(&cnt[sb[i] >> 17], 1);
    __syncthreads();
    int c0 = cnt[2 * t], c1 = cnt[2 * t + 1];
    s[t] = c0 + c1;
    __syncthreads();
    for (int off = 1; off < 256; off <<= 1) {
        int a = (t >= off) ? s[t - off] : 0;
        __syncthreads();
        s[t] += a;
        __syncthreads();
    }
    int ex = s[t] - c0 - c1;
    rstart[2 * t] = ex;
    rstart[2 * t + 1] = ex + c0;
    __syncthreads();
    for (int i = t; i < ROWS_PB; i += 256) {
        int g = b * ROWS_PB + i;
        if (g < N_NODES) {
            rowptr[g] = gbase + rstart[i];
            dinv[g] = rsqrtf((float)(cnt[i] + 1));   // +1 self-loop
        }
    }
    __syncthreads();
    for (int i = t; i < ROWS_PB; i += 256) cnt[i] = 0;  // reuse as cursor
    __syncthreads();
    for (int i = t; i < n; i += 256) {
        unsigned int v = sb[i];
        int lr = v >> 17;
        int pos = atomicAdd(&cnt[lr], 1);
        colv[gbase + rstart[lr] + pos] = (int)(v & 0x1FFFFu);
    }
}

// ---- GEMM1: Hs = (x @ W1) * dinv, 64 rows x 4 wave-uniform K-chunks/block ----
#define GROWS 64
#define RPAD 17

__global__ __launch_bounds__(256) void k_gemm1(const float* __restrict__ x,
                                               const float* __restrict__ W1,
                                               const float* __restrict__ dinv,
                                               float* __restrict__ Hs) {
    __shared__ float red[4 * GROWS * RPAD];   // 17.4 KB
    int t = threadIdx.x;
    int kc = t >> 6;              // wave-uniform K-chunk id (128 k each) -> W1 via s_load
    int rl = t & 63;
    int row = blockIdx.x * GROWS + rl;

    float acc[HID];
#pragma unroll
    for (int f = 0; f < HID; ++f) acc[f] = 0.0f;

    if (row < N_NODES) {
        const float* xp = x + (size_t)row * F_IN + kc * 128;
        const float* wp = W1 + kc * 128 * HID;
        float4 a = *reinterpret_cast<const float4*>(xp);
        float4 b = *reinterpret_cast<const float4*>(xp + 4);
        for (int k = 0; k < 128; k += 8) {
            float4 na, nb;
            if (k + 8 < 128) {
                na = *reinterpret_cast<const float4*>(xp + k + 8);
                nb = *reinterpret_cast<const float4*>(xp + k + 12);
            } else {
                na = a; nb = b;
            }
            float xs[8] = {a.x, a.y, a.z, a.w, b.x, b.y, b.z, b.w};
#pragma unroll
            for (int kk = 0; kk < 8; ++kk) {
                float xv = xs[kk];
#pragma unroll
                for (int f = 0; f < HID; ++f)
                    acc[f] = fmaf(xv, wp[(k + kk) * HID + f], acc[f]);  // uniform -> s_load
            }
            a = na; b = nb;
        }
    }
    int base = (kc * GROWS + rl) * RPAD;
#pragma unroll
    for (int f = 0; f < HID; ++f) red[base + f] = acc[f];
    __syncthreads();
#pragma unroll
    for (int p = 0; p < 4; ++p) {
        int o = p * 256 + t;                  // 0..1023 = 64 rows x 16 f
        int r = o >> 4, f = o & 15;
        int rg = blockIdx.x * GROWS + r;
        if (rg < N_NODES) {
            float s = red[(0 * GROWS + r) * RPAD + f] + red[(1 * GROWS + r) * RPAD + f] +
                      red[(2 * GROWS + r) * RPAD + f] + red[(3 * GROWS + r) * RPAD + f];
            Hs[(size_t)rg * HID + f] = s * dinv[rg];
        }
    }
}

// ------- agg1: wave/node pull of Hs, fused bias+relu, store h1s = dinv*h1 ----
__global__ __launch_bounds__(256) void k_agg1(const int* __restrict__ rowptr,
                                              const int* __restrict__ colv,
                                              const float* __restrict__ dinv,
                                              const float* __restrict__ Hs,
                                              const float* __restrict__ b1,
                                              float* __restrict__ h1s) {
    int wid = (blockIdx.x * 256 + threadIdx.x) >> 6;
    if (wid >= N_NODES) return;
    int lane = threadIdx.x & 63;
    int f = lane & 15, sub = lane >> 4;
    int beg = rowptr[wid], end = rowptr[wid + 1];
    float acc = 0.0f;
    for (int j = beg + sub; j < end; j += 4)
        acc += Hs[(size_t)colv[j] * HID + f];
    acc += __shfl_xor(acc, 16);
    acc += __shfl_xor(acc, 32);
    if (lane < 16) {
        float dr = dinv[wid];
        float v = (acc + Hs[(size_t)wid * HID + f]) * dr + b1[f];   // self folds in
        h1s[(size_t)wid * HID + f] = fmaxf(v, 0.0f) * dr;
    }
}

// ------- agg2: wave/node pull of h1s, fused 16x40 GEMM + bias -> out ---------
__global__ __launch_bounds__(256) void k_agg2(const int* __restrict__ rowptr,
                                              const int* __restrict__ colv,
                                              const float* __restrict__ dinv,
                                              const float* __restrict__ h1s,
                                              const float* __restrict__ W2,
                                              const float* __restrict__ b2,
                                              float* __restrict__ out) {
    int wid = (blockIdx.x * 256 + threadIdx.x) >> 6;
    if (wid >= N_NODES) return;
    int lane = threadIdx.x & 63;
    int f = lane & 15, sub = lane >> 4;
    int beg = rowptr[wid], end = rowptr[wid + 1];
    float acc = 0.0f;
    for (int j = beg + sub; j < end; j += 4)
        acc += h1s[(size_t)colv[j] * HID + f];
    acc += __shfl_xor(acc, 16);
    acc += __shfl_xor(acc, 32);
    float w = (acc + h1s[(size_t)wid * HID + f]) * dinv[wid];   // pre-W2, slot f
    if (lane < F_OUT) {
        float o = b2[lane];
#pragma unroll
        for (int k = 0; k < HID; ++k)
            o = fmaf(__shfl(w, k), W2[k * F_OUT + lane], o);
        out[(size_t)wid * F_OUT + lane] = o;
    }
}

// ---------------- launch ----------------
extern "C" void kernel_launch(void* const* d_in, const int* in_sizes, int n_in,
                              void* d_out, int out_size, void* d_ws, size_t ws_size,
                              hipStream_t stream) {
    const float* x  = (const float*)d_in[0];
    const int* ei   = (const int*)d_in[1];      // int32 [2][E]
    const float* W1 = (const float*)d_in[2];
    const float* b1 = (const float*)d_in[3];
    const float* W2 = (const float*)d_in[4];
    const float* b2 = (const float*)d_in[5];
    float* out = (float*)d_out;
    const int E = in_sizes[1] / 2;

    // ws layout (4B units, 64B-aligned sections)
    int* gcursor          = (int*)d_ws;                      // 3136 (+pad)
    int* bucketBase       = gcursor + 3200;                  // 197 -> pad 256
    int* rowptr           = bucketBase + 256;                // 100001 -> pad
    float* dinv           = (float*)(rowptr + 100016);       // 100000
    int* colv             = (int*)(dinv + 100000);           // 3,200,000
    unsigned int* sortbuf = (unsigned int*)(colv + 3200000); // 196*17408 = 3,411,968
    float* Hs             = (float*)sortbuf;                 // alias: dead after k_build
    float* h1s            = (float*)(sortbuf + 3411968);     // N*16
    // total ~33.7 MB

    const int nbW = (N_NODES * 64 + 255) / 256;    // 25000 (wave per node)
    const int nbG = (N_NODES + GROWS - 1) / GROWS; // 1563

    k_zero<<<(NB * CUR_PAD + 255) / 256, 256, 0, stream>>>(gcursor);
    k_part1<<<256, 256, 0, stream>>>(ei, E, gcursor, sortbuf);
    k_bscan<<<1, 256, 0, stream>>>(gcursor, bucketBase, rowptr);
    k_build<<<NB, 256, 0, stream>>>(sortbuf, gcursor, bucketBase, rowptr, dinv, colv);

    k_gemm1<<<nbG, 256, 0, stream>>>(x, W1, dinv, Hs);

    k_agg1<<<nbW, 256, 0, stream>>>(rowptr, colv, dinv, Hs, b1, h1s);
    k_agg2<<<nbW, 256, 0, stream>>>(rowptr, colv, dinv, h1s, W2, b2, out);
}

// Round 7
// 316.185 us; speedup vs baseline: 1.2824x; 1.2824x over previous
//
#include <hip/hip_runtime.h>

#define N_NODES 100000
#define F_IN 512
#define HID 16
#define F_OUT 40

#define NB 196        // buckets = row >> 9
#define BSHIFT 9
#define ROWS_PB 512
#define BCAP 17408    // mean 16384 + 8 sigma
#define CUR_PAD 16    // gcursor stride in ints (64B: one counter per line)

// ---------------- zero gcursor ----------------
__global__ void k_zero(int* __restrict__ g) {
    int i = blockIdx.x * 256 + threadIdx.x;
    if (i < NB * CUR_PAD) g[i] = 0;
}

// ---------------- pass 1: bucket scatter (packed u32) ----------------
__global__ __launch_bounds__(256) void k_part1(const int* __restrict__ ei, int E,
                                               int* __restrict__ gcursor,
                                               unsigned int* __restrict__ sortbuf) {
    __shared__ int cnt[NB];
    __shared__ int gb[NB];
    int t = threadIdx.x;
    int epb = (E + gridDim.x - 1) / gridDim.x;
    int base = blockIdx.x * epb;
    int lim = min(base + epb, E);
    for (int cbase = base; cbase < lim; cbase += 4096) {
        int cend = min(cbase + 4096, lim);
        for (int i = t; i < NB; i += 256) cnt[i] = 0;
        __syncthreads();
        unsigned int v[16];
        int bkt[16], mi[16];
#pragma unroll
        for (int i = 0; i < 16; ++i) {
            int e = cbase + i * 256 + t;
            bkt[i] = -1;
            if (e < cend) {
                int r = ei[e], c = ei[E + e];
                bkt[i] = r >> BSHIFT;
                v[i] = ((unsigned)(r & (ROWS_PB - 1)) << 17) | (unsigned)c;
                mi[i] = atomicAdd(&cnt[bkt[i]], 1);
            }
        }
        __syncthreads();
        for (int i = t; i < NB; i += 256)
            gb[i] = atomicAdd(&gcursor[i * CUR_PAD], cnt[i]);
        __syncthreads();
#pragma unroll
        for (int i = 0; i < 16; ++i)
            if (bkt[i] >= 0) {
                int idx = gb[bkt[i]] + mi[i];
                if (idx < BCAP) sortbuf[(size_t)bkt[i] * BCAP + idx] = v[i];
            }
        __syncthreads();
    }
}

// ---------------- bucket scan (single block) ----------------
__global__ __launch_bounds__(256) void k_bscan(const int* __restrict__ gcursor,
                                               int* __restrict__ bucketBase,
                                               int* __restrict__ rowptr) {
    __shared__ int s[256];
    int t = threadIdx.x;
    int v = (t < NB) ? min(gcursor[t * CUR_PAD], BCAP) : 0;
    s[t] = v;
    __syncthreads();
    for (int off = 1; off < 256; off <<= 1) {
        int a = (t >= off) ? s[t - off] : 0;
        __syncthreads();
        s[t] += a;
        __syncthreads();
    }
    if (t < NB) bucketBase[t] = s[t] - v;
    if (t == NB - 1) { bucketBase[NB] = s[t]; rowptr[N_NODES] = s[t]; }
}

// ---------------- pass 2: per-bucket CSR build ----------------
__global__ __launch_bounds__(256) void k_build(const unsigned int* __restrict__ sortbuf,
                                               const int* __restrict__ gcursor,
                                               const int* __restrict__ bucketBase,
                                               int* __restrict__ rowptr,
                                               float* __restrict__ dinv,
                                               int* __restrict__ colv) {
    __shared__ int cnt[ROWS_PB];
    __shared__ int rstart[ROWS_PB];
    __shared__ int s[256];
    int b = blockIdx.x, t = threadIdx.x;
    int n = min(gcursor[b * CUR_PAD], BCAP);
    const unsigned int* sb = sortbuf + (size_t)b * BCAP;
    int gbase = bucketBase[b];
    for (int i = t; i < ROWS_PB; i += 256) cnt[i] = 0;
    __syncthreads();
    for (int i = t; i < n; i += 256) atomicAdd(&cnt[sb[i] >> 17], 1);
    __syncthreads();
    int c0 = cnt[2 * t], c1 = cnt[2 * t + 1];
    s[t] = c0 + c1;
    __syncthreads();
    for (int off = 1; off < 256; off <<= 1) {
        int a = (t >= off) ? s[t - off] : 0;
        __syncthreads();
        s[t] += a;
        __syncthreads();
    }
    int ex = s[t] - c0 - c1;
    rstart[2 * t] = ex;
    rstart[2 * t + 1] = ex + c0;
    __syncthreads();
    for (int i = t; i < ROWS_PB; i += 256) {
        int g = b * ROWS_PB + i;
        if (g < N_NODES) {
            rowptr[g] = gbase + rstart[i];
            dinv[g] = rsqrtf((float)(cnt[i] + 1));   // +1 self-loop
        }
    }
    __syncthreads();
    for (int i = t; i < ROWS_PB; i += 256) cnt[i] = 0;  // reuse as cursor
    __syncthreads();
    for (int i = t; i < n; i += 256) {
        unsigned int v = sb[i];
        int lr = v >> 17;
        int pos = atomicAdd(&cnt[lr], 1);
        colv[gbase + rstart[lr] + pos] = (int)(v & 0x1FFFFu);
    }
}

// ---- GEMM1: Hs = (x @ W1) * dinv, 64 rows x 4 wave-uniform K-chunks/block ----
#define GROWS 64
#define RPAD 17

__global__ __launch_bounds__(256) void k_gemm1(const float* __restrict__ x,
                                               const float* __restrict__ W1,
                                               const float* __restrict__ dinv,
                                               float* __restrict__ Hs) {
    __shared__ float red[4 * GROWS * RPAD];   // 17.4 KB
    int t = threadIdx.x;
    // wave-uniform K-chunk id: readfirstlane forces SGPR -> W1 reads stay s_load
    int kc = __builtin_amdgcn_readfirstlane(t >> 6);
    int rl = t & 63;
    int row = blockIdx.x * GROWS + rl;

    float acc[HID];
#pragma unroll
    for (int f = 0; f < HID; ++f) acc[f] = 0.0f;

    if (row < N_NODES) {
        const float* xp = x + (size_t)row * F_IN + kc * 128;
        const float* wp = W1 + kc * 128 * HID;
        // 64B/lane per step: 4 x float4 covering k..k+15, 1-deep prefetch
        float4 a0 = *reinterpret_cast<const float4*>(xp);
        float4 a1 = *reinterpret_cast<const float4*>(xp + 4);
        float4 a2 = *reinterpret_cast<const float4*>(xp + 8);
        float4 a3 = *reinterpret_cast<const float4*>(xp + 12);
        for (int k = 0; k < 128; k += 16) {
            float4 n0, n1, n2, n3;
            if (k + 16 < 128) {
                n0 = *reinterpret_cast<const float4*>(xp + k + 16);
                n1 = *reinterpret_cast<const float4*>(xp + k + 20);
                n2 = *reinterpret_cast<const float4*>(xp + k + 24);
                n3 = *reinterpret_cast<const float4*>(xp + k + 28);
            } else {
                n0 = a0; n1 = a1; n2 = a2; n3 = a3;
            }
            float xs[16] = {a0.x, a0.y, a0.z, a0.w, a1.x, a1.y, a1.z, a1.w,
                            a2.x, a2.y, a2.z, a2.w, a3.x, a3.y, a3.z, a3.w};
#pragma unroll
            for (int kk = 0; kk < 16; ++kk) {
                float xv = xs[kk];
#pragma unroll
                for (int f = 0; f < HID; ++f)
                    acc[f] = fmaf(xv, wp[(k + kk) * HID + f], acc[f]);  // s_load
            }
            a0 = n0; a1 = n1; a2 = n2; a3 = n3;
        }
    }
    int base = (kc * GROWS + rl) * RPAD;
#pragma unroll
    for (int f = 0; f < HID; ++f) red[base + f] = acc[f];
    __syncthreads();
#pragma unroll
    for (int p = 0; p < 4; ++p) {
        int o = p * 256 + t;                  // 0..1023 = 64 rows x 16 f
        int r = o >> 4, f = o & 15;
        int rg = blockIdx.x * GROWS + r;
        if (rg < N_NODES) {
            float s = red[(0 * GROWS + r) * RPAD + f] + red[(1 * GROWS + r) * RPAD + f] +
                      red[(2 * GROWS + r) * RPAD + f] + red[(3 * GROWS + r) * RPAD + f];
            Hs[(size_t)rg * HID + f] = s * dinv[rg];
        }
    }
}

// ------- agg1: wave/node pull of Hs, fused bias+relu, store h1s = dinv*h1 ----
__global__ __launch_bounds__(256) void k_agg1(const int* __restrict__ rowptr,
                                              const int* __restrict__ colv,
                                              const float* __restrict__ dinv,
                                              const float* __restrict__ Hs,
                                              const float* __restrict__ b1,
                                              float* __restrict__ h1s) {
    int wid = (blockIdx.x * 256 + threadIdx.x) >> 6;
    if (wid >= N_NODES) return;
    int lane = threadIdx.x & 63;
    int f = lane & 15, sub = lane >> 4;
    int beg = rowptr[wid], end = rowptr[wid + 1];
    float acc = 0.0f;
    for (int j = beg + sub; j < end; j += 4)
        acc += Hs[(size_t)colv[j] * HID + f];
    acc += __shfl_xor(acc, 16);
    acc += __shfl_xor(acc, 32);
    if (lane < 16) {
        float dr = dinv[wid];
        float v = (acc + Hs[(size_t)wid * HID + f]) * dr + b1[f];   // self folds in
        h1s[(size_t)wid * HID + f] = fmaxf(v, 0.0f) * dr;
    }
}

// ------- agg2: wave/node pull of h1s, fused 16x40 GEMM + bias -> out ---------
__global__ __launch_bounds__(256) void k_agg2(const int* __restrict__ rowptr,
                                              const int* __restrict__ colv,
                                              const float* __restrict__ dinv,
                                              const float* __restrict__ h1s,
                                              const float* __restrict__ W2,
                                              const float* __restrict__ b2,
                                              float* __restrict__ out) {
    int wid = (blockIdx.x * 256 + threadIdx.x) >> 6;
    if (wid >= N_NODES) return;
    int lane = threadIdx.x & 63;
    int f = lane & 15, sub = lane >> 4;
    int beg = rowptr[wid], end = rowptr[wid + 1];
    float acc = 0.0f;
    for (int j = beg + sub; j < end; j += 4)
        acc += h1s[(size_t)colv[j] * HID + f];
    acc += __shfl_xor(acc, 16);
    acc += __shfl_xor(acc, 32);
    float w = (acc + h1s[(size_t)wid * HID + f]) * dinv[wid];   // pre-W2, slot f
    if (lane < F_OUT) {
        float o = b2[lane];
#pragma unroll
        for (int k = 0; k < HID; ++k)
            o = fmaf(__shfl(w, k), W2[k * F_OUT + lane], o);
        out[(size_t)wid * F_OUT + lane] = o;
    }
}

// ---------------- launch ----------------
extern "C" void kernel_launch(void* const* d_in, const int* in_sizes, int n_in,
                              void* d_out, int out_size, void* d_ws, size_t ws_size,
                              hipStream_t stream) {
    const float* x  = (const float*)d_in[0];
    const int* ei   = (const int*)d_in[1];      // int32 [2][E]
    const float* W1 = (const float*)d_in[2];
    const float* b1 = (const float*)d_in[3];
    const float* W2 = (const float*)d_in[4];
    const float* b2 = (const float*)d_in[5];
    float* out = (float*)d_out;
    const int E = in_sizes[1] / 2;

    // ws layout (4B units, 64B-aligned sections)
    int* gcursor          = (int*)d_ws;                      // 3136 (+pad)
    int* bucketBase       = gcursor + 3200;                  // 197 -> pad 256
    int* rowptr           = bucketBase + 256;                // 100001 -> pad
    float* dinv           = (float*)(rowptr + 100016);       // 100000
    int* colv             = (int*)(dinv + 100000);           // 3,200,000
    unsigned int* sortbuf = (unsigned int*)(colv + 3200000); // 196*17408 = 3,411,968
    float* Hs             = (float*)sortbuf;                 // alias: dead after k_build
    float* h1s            = (float*)(sortbuf + 3411968);     // N*16
    // total ~33.7 MB

    const int nbW = (N_NODES * 64 + 255) / 256;    // 25000 (wave per node)
    const int nbG = (N_NODES + GROWS - 1) / GROWS; // 1563

    k_zero<<<(NB * CUR_PAD + 255) / 256, 256, 0, stream>>>(gcursor);
    k_part1<<<256, 256, 0, stream>>>(ei, E, gcursor, sortbuf);
    k_bscan<<<1, 256, 0, stream>>>(gcursor, bucketBase, rowptr);
    k_build<<<NB, 256, 0, stream>>>(sortbuf, gcursor, bucketBase, rowptr, dinv, colv);

    k_gemm1<<<nbG, 256, 0, stream>>>(x, W1, dinv, Hs);

    k_agg1<<<nbW, 256, 0, stream>>>(rowptr, colv, dinv, Hs, b1, h1s);
    k_agg2<<<nbW, 256, 0, stream>>>(rowptr, colv, dinv, h1s, W2, b2, out);
}

// Round 8
// 247.557 us; speedup vs baseline: 1.6380x; 1.2772x over previous
//
#include <hip/hip_runtime.h>

#define N_NODES 100000
#define F_IN 512
#define HID 16
#define F_OUT 40

#define NB 784        // buckets = row >> 7
#define BSHIFT 7
#define ROWS_PB 128
#define BCAP 4608     // mean 4082 + 8 sigma
#define CUR_PAD 16    // gcursor stride in ints (64B: one counter per line)

// ---------------- zero gcursor ----------------
__global__ void k_zero(int* __restrict__ g) {
    int i = blockIdx.x * 256 + threadIdx.x;
    if (i < NB * CUR_PAD) g[i] = 0;
}

// ---------------- pass 1: bucket scatter (packed u32) ----------------
__global__ __launch_bounds__(256) void k_part1(const int* __restrict__ ei, int E,
                                               int* __restrict__ gcursor,
                                               unsigned int* __restrict__ sortbuf) {
    __shared__ int cnt[NB];
    __shared__ int gb[NB];
    int t = threadIdx.x;
    int epb = (E + gridDim.x - 1) / gridDim.x;
    int base = blockIdx.x * epb;
    int lim = min(base + epb, E);
    for (int cbase = base; cbase < lim; cbase += 4096) {
        int cend = min(cbase + 4096, lim);
        for (int i = t; i < NB; i += 256) cnt[i] = 0;
        __syncthreads();
        unsigned int v[16];
        int bkt[16], mi[16];
#pragma unroll
        for (int i = 0; i < 16; ++i) {
            int e = cbase + i * 256 + t;
            bkt[i] = -1;
            if (e < cend) {
                int r = ei[e], c = ei[E + e];
                bkt[i] = r >> BSHIFT;
                v[i] = ((unsigned)(r & (ROWS_PB - 1)) << 17) | (unsigned)c;
                mi[i] = atomicAdd(&cnt[bkt[i]], 1);
            }
        }
        __syncthreads();
        for (int i = t; i < NB; i += 256)
            gb[i] = atomicAdd(&gcursor[i * CUR_PAD], cnt[i]);
        __syncthreads();
#pragma unroll
        for (int i = 0; i < 16; ++i)
            if (bkt[i] >= 0) {
                int idx = gb[bkt[i]] + mi[i];
                if (idx < BCAP) sortbuf[(size_t)bkt[i] * BCAP + idx] = v[i];
            }
        __syncthreads();
    }
}

// ---------------- bucket scan (single 1024-thread block) ----------------
__global__ __launch_bounds__(1024) void k_bscan(const int* __restrict__ gcursor,
                                                int* __restrict__ bucketBase,
                                                int* __restrict__ rowptr) {
    __shared__ int s[1024];
    int t = threadIdx.x;
    int v = (t < NB) ? min(gcursor[t * CUR_PAD], BCAP) : 0;
    s[t] = v;
    __syncthreads();
    for (int off = 1; off < 1024; off <<= 1) {
        int a = (t >= off) ? s[t - off] : 0;
        __syncthreads();
        s[t] += a;
        __syncthreads();
    }
    if (t < NB) bucketBase[t] = s[t] - v;
    if (t == NB - 1) { bucketBase[NB] = s[t]; rowptr[N_NODES] = s[t]; }
}

// ---------------- pass 2: per-bucket CSR build (784 blocks) ----------------
__global__ __launch_bounds__(256) void k_build(const unsigned int* __restrict__ sortbuf,
                                               const int* __restrict__ gcursor,
                                               const int* __restrict__ bucketBase,
                                               int* __restrict__ rowptr,
                                               float* __restrict__ dinv,
                                               int* __restrict__ colv) {
    __shared__ int cnt[ROWS_PB];
    __shared__ int rstart[ROWS_PB];
    __shared__ int s[256];
    int b = blockIdx.x, t = threadIdx.x;
    int n = min(gcursor[b * CUR_PAD], BCAP);
    const unsigned int* sb = sortbuf + (size_t)b * BCAP;
    int gbase = bucketBase[b];
    if (t < ROWS_PB) cnt[t] = 0;
    __syncthreads();
    for (int i = t; i < n; i += 256) atomicAdd(&cnt[sb[i] >> 17], 1);
    __syncthreads();
    int c0 = (t < ROWS_PB) ? cnt[t] : 0;
    s[t] = c0;
    __syncthreads();
    for (int off = 1; off < 256; off <<= 1) {
        int a = (t >= off) ? s[t - off] : 0;
        __syncthreads();
        s[t] += a;
        __syncthreads();
    }
    if (t < ROWS_PB) {
        int ex = s[t] - c0;
        rstart[t] = ex;
        int g = b * ROWS_PB + t;
        if (g < N_NODES) {
            rowptr[g] = gbase + ex;
            dinv[g] = rsqrtf((float)(c0 + 1));   // +1 self-loop
        }
    }
    __syncthreads();
    if (t < ROWS_PB) cnt[t] = 0;  // reuse as cursor
    __syncthreads();
    for (int i = t; i < n; i += 256) {
        unsigned int v = sb[i];
        int lr = v >> 17;
        int pos = atomicAdd(&cnt[lr], 1);
        colv[gbase + rstart[lr] + pos] = (int)(v & 0x1FFFFu);
    }
}

// ---- GEMM1: Hs = (x @ W1) * dinv, 64 rows x 4 wave-uniform K-chunks/block ----
#define GROWS 64
#define RPAD 17

__global__ __launch_bounds__(256) void k_gemm1(const float* __restrict__ x,
                                               const float* __restrict__ W1,
                                               const float* __restrict__ dinv,
                                               float* __restrict__ Hs) {
    __shared__ float red[4 * GROWS * RPAD];   // 17.4 KB
    int t = threadIdx.x;
    // wave-uniform K-chunk id: readfirstlane forces SGPR -> W1 reads stay s_load
    int kc = __builtin_amdgcn_readfirstlane(t >> 6);
    int rl = t & 63;
    int row = blockIdx.x * GROWS + rl;

    float acc[HID];
#pragma unroll
    for (int f = 0; f < HID; ++f) acc[f] = 0.0f;

    if (row < N_NODES) {
        const float* xp = x + (size_t)row * F_IN + kc * 128;
        const float* wp = W1 + kc * 128 * HID;
        float4 a0 = *reinterpret_cast<const float4*>(xp);
        float4 a1 = *reinterpret_cast<const float4*>(xp + 4);
        float4 a2 = *reinterpret_cast<const float4*>(xp + 8);
        float4 a3 = *reinterpret_cast<const float4*>(xp + 12);
        for (int k = 0; k < 128; k += 16) {
            float4 n0, n1, n2, n3;
            if (k + 16 < 128) {
                n0 = *reinterpret_cast<const float4*>(xp + k + 16);
                n1 = *reinterpret_cast<const float4*>(xp + k + 20);
                n2 = *reinterpret_cast<const float4*>(xp + k + 24);
                n3 = *reinterpret_cast<const float4*>(xp + k + 28);
            } else {
                n0 = a0; n1 = a1; n2 = a2; n3 = a3;
            }
            float xs[16] = {a0.x, a0.y, a0.z, a0.w, a1.x, a1.y, a1.z, a1.w,
                            a2.x, a2.y, a2.z, a2.w, a3.x, a3.y, a3.z, a3.w};
#pragma unroll
            for (int kk = 0; kk < 16; ++kk) {
                float xv = xs[kk];
#pragma unroll
                for (int f = 0; f < HID; ++f)
                    acc[f] = fmaf(xv, wp[(k + kk) * HID + f], acc[f]);  // s_load
            }
            a0 = n0; a1 = n1; a2 = n2; a3 = n3;
        }
    }
    int base = (kc * GROWS + rl) * RPAD;
#pragma unroll
    for (int f = 0; f < HID; ++f) red[base + f] = acc[f];
    __syncthreads();
#pragma unroll
    for (int p = 0; p < 4; ++p) {
        int o = p * 256 + t;                  // 0..1023 = 64 rows x 16 f
        int r = o >> 4, f = o & 15;
        int rg = blockIdx.x * GROWS + r;
        if (rg < N_NODES) {
            float s = red[(0 * GROWS + r) * RPAD + f] + red[(1 * GROWS + r) * RPAD + f] +
                      red[(2 * GROWS + r) * RPAD + f] + red[(3 * GROWS + r) * RPAD + f];
            Hs[(size_t)rg * HID + f] = s * dinv[rg];
        }
    }
}

// -- agg1: wave/node pull, float4 gathers (16 edges in flight), bias+relu ----
__global__ __launch_bounds__(256) void k_agg1(const int* __restrict__ rowptr,
                                              const int* __restrict__ colv,
                                              const float* __restrict__ dinv,
                                              const float* __restrict__ Hs,
                                              const float* __restrict__ b1,
                                              float* __restrict__ h1s) {
    int wid = (blockIdx.x * 256 + threadIdx.x) >> 6;
    if (wid >= N_NODES) return;
    int lane = threadIdx.x & 63;
    int f4 = lane & 3, sub = lane >> 2;
    int beg = rowptr[wid], end = rowptr[wid + 1];
    float4 acc = make_float4(0.f, 0.f, 0.f, 0.f);
    for (int j = beg + sub; j < end; j += 16) {
        int c = colv[j];
        float4 hv = *reinterpret_cast<const float4*>(Hs + (size_t)c * HID + f4 * 4);
        acc.x += hv.x; acc.y += hv.y; acc.z += hv.z; acc.w += hv.w;
    }
#pragma unroll
    for (int d = 4; d < 64; d <<= 1) {
        acc.x += __shfl_xor(acc.x, d);
        acc.y += __shfl_xor(acc.y, d);
        acc.z += __shfl_xor(acc.z, d);
        acc.w += __shfl_xor(acc.w, d);
    }
    if (sub == 0) {
        float dr = dinv[wid];
        float4 self = *reinterpret_cast<const float4*>(Hs + (size_t)wid * HID + f4 * 4);
        float4 bb = *reinterpret_cast<const float4*>(b1 + f4 * 4);
        float4 o;
        o.x = fmaxf((acc.x + self.x) * dr + bb.x, 0.f) * dr;
        o.y = fmaxf((acc.y + self.y) * dr + bb.y, 0.f) * dr;
        o.z = fmaxf((acc.z + self.z) * dr + bb.z, 0.f) * dr;
        o.w = fmaxf((acc.w + self.w) * dr + bb.w, 0.f) * dr;
        *reinterpret_cast<float4*>(h1s + (size_t)wid * HID + f4 * 4) = o;
    }
}

// -- agg2: wave/node pull of h1s (float4), fused 16x40 GEMM + bias -> out -----
__global__ __launch_bounds__(256) void k_agg2(const int* __restrict__ rowptr,
                                              const int* __restrict__ colv,
                                              const float* __restrict__ dinv,
                                              const float* __restrict__ h1s,
                                              const float* __restrict__ W2,
                                              const float* __restrict__ b2,
                                              float* __restrict__ out) {
    int wid = (blockIdx.x * 256 + threadIdx.x) >> 6;
    if (wid >= N_NODES) return;
    int lane = threadIdx.x & 63;
    int f4 = lane & 3, sub = lane >> 2;
    int beg = rowptr[wid], end = rowptr[wid + 1];
    float4 acc = make_float4(0.f, 0.f, 0.f, 0.f);
    for (int j = beg + sub; j < end; j += 16) {
        int c = colv[j];
        float4 hv = *reinterpret_cast<const float4*>(h1s + (size_t)c * HID + f4 * 4);
        acc.x += hv.x; acc.y += hv.y; acc.z += hv.z; acc.w += hv.w;
    }
#pragma unroll
    for (int d = 4; d < 64; d <<= 1) {
        acc.x += __shfl_xor(acc.x, d);
        acc.y += __shfl_xor(acc.y, d);
        acc.z += __shfl_xor(acc.z, d);
        acc.w += __shfl_xor(acc.w, d);
    }
    // all lanes now hold the 4-feature aggregate for their f4 slot
    float dr = dinv[wid];
    float4 self = *reinterpret_cast<const float4*>(h1s + (size_t)wid * HID + f4 * 4);
    float4 w4;
    w4.x = (acc.x + self.x) * dr;
    w4.y = (acc.y + self.y) * dr;
    w4.z = (acc.z + self.z) * dr;
    w4.w = (acc.w + self.w) * dr;
    if (lane < F_OUT) {
        float o = b2[lane];
#pragma unroll
        for (int k = 0; k < HID; ++k) {
            float comp = (k & 3) == 0 ? w4.x : (k & 3) == 1 ? w4.y
                        : (k & 3) == 2 ? w4.z : w4.w;
            float wk = __shfl(comp, k >> 2);   // lane k>>2 has f4 == k>>2
            o = fmaf(wk, W2[k * F_OUT + lane], o);
        }
        out[(size_t)wid * F_OUT + lane] = o;
    }
}

// ---------------- launch ----------------
extern "C" void kernel_launch(void* const* d_in, const int* in_sizes, int n_in,
                              void* d_out, int out_size, void* d_ws, size_t ws_size,
                              hipStream_t stream) {
    const float* x  = (const float*)d_in[0];
    const int* ei   = (const int*)d_in[1];      // int32 [2][E]
    const float* W1 = (const float*)d_in[2];
    const float* b1 = (const float*)d_in[3];
    const float* W2 = (const float*)d_in[4];
    const float* b2 = (const float*)d_in[5];
    float* out = (float*)d_out;
    const int E = in_sizes[1] / 2;

    // ws layout (4B units, 64B-aligned sections)
    int* gcursor          = (int*)d_ws;                      // 784*16 = 12544
    int* bucketBase       = gcursor + 12544;                 // 785 -> pad 800
    int* rowptr           = bucketBase + 800;                // 100001 -> pad
    float* dinv           = (float*)(rowptr + 100016);       // 100000
    int* colv             = (int*)(dinv + 100000);           // 3,200,000
    unsigned int* sortbuf = (unsigned int*)(colv + 3200000); // 784*4608 = 3,612,672
    float* Hs             = (float*)sortbuf;                 // alias: dead after k_build
    float* h1s            = (float*)(sortbuf + 3612672);     // N*16
    // total ~34.6 MB

    const int nbW = (N_NODES * 64 + 255) / 256;    // 25000 (wave per node)
    const int nbG = (N_NODES + GROWS - 1) / GROWS; // 1563

    k_zero<<<(NB * CUR_PAD + 255) / 256, 256, 0, stream>>>(gcursor);
    k_part1<<<256, 256, 0, stream>>>(ei, E, gcursor, sortbuf);
    k_bscan<<<1, 1024, 0, stream>>>(gcursor, bucketBase, rowptr);
    k_build<<<NB, 256, 0, stream>>>(sortbuf, gcursor, bucketBase, rowptr, dinv, colv);

    k_gemm1<<<nbG, 256, 0, stream>>>(x, W1, dinv, Hs);

    k_agg1<<<nbW, 256, 0, stream>>>(rowptr, colv, dinv, Hs, b1, h1s);
    k_agg2<<<nbW, 256, 0, stream>>>(rowptr, colv, dinv, h1s, W2, b2, out);
}

// Round 9
// 238.252 us; speedup vs baseline: 1.7019x; 1.0391x over previous
//
#include <hip/hip_runtime.h>

#define N_NODES 100000
#define F_IN 512
#define HID 16
#define F_OUT 40

#define NB 784        // buckets = row >> 7
#define BSHIFT 7
#define ROWS_PB 128
#define BCAP 4608     // mean 4082 + 8 sigma
#define CUR_PAD 16    // gcursor stride in ints (64B: one counter per line)

// ---------------- zero gcursor ----------------
__global__ void k_zero(int* __restrict__ g) {
    int i = blockIdx.x * 256 + threadIdx.x;
    if (i < NB * CUR_PAD) g[i] = 0;
}

// ---------------- pass 1: bucket scatter (packed u32) ----------------
__global__ __launch_bounds__(256) void k_part1(const int* __restrict__ ei, int E,
                                               int* __restrict__ gcursor,
                                               unsigned int* __restrict__ sortbuf) {
    __shared__ int cnt[NB];
    __shared__ int gb[NB];
    int t = threadIdx.x;
    int epb = (E + gridDim.x - 1) / gridDim.x;
    int base = blockIdx.x * epb;
    int lim = min(base + epb, E);
    for (int cbase = base; cbase < lim; cbase += 4096) {
        int cend = min(cbase + 4096, lim);
        for (int i = t; i < NB; i += 256) cnt[i] = 0;
        __syncthreads();
        unsigned int v[16];
        int bkt[16], mi[16];
#pragma unroll
        for (int i = 0; i < 16; ++i) {
            int e = cbase + i * 256 + t;
            bkt[i] = -1;
            if (e < cend) {
                int r = ei[e], c = ei[E + e];
                bkt[i] = r >> BSHIFT;
                v[i] = ((unsigned)(r & (ROWS_PB - 1)) << 17) | (unsigned)c;
                mi[i] = atomicAdd(&cnt[bkt[i]], 1);
            }
        }
        __syncthreads();
        for (int i = t; i < NB; i += 256)
            gb[i] = atomicAdd(&gcursor[i * CUR_PAD], cnt[i]);
        __syncthreads();
#pragma unroll
        for (int i = 0; i < 16; ++i)
            if (bkt[i] >= 0) {
                int idx = gb[bkt[i]] + mi[i];
                if (idx < BCAP) sortbuf[(size_t)bkt[i] * BCAP + idx] = v[i];
            }
        __syncthreads();
    }
}

// ---- pass 2: per-bucket CSR build; each block self-computes the bucket scan --
__global__ __launch_bounds__(256) void k_build(const unsigned int* __restrict__ sortbuf,
                                               const int* __restrict__ gcursor,
                                               int* __restrict__ rowptr,
                                               float* __restrict__ dinv,
                                               int* __restrict__ colv) {
    __shared__ int bb[NB];          // exclusive bucket bases
    __shared__ int s[256];
    __shared__ int cnt[ROWS_PB];
    __shared__ int rstart[ROWS_PB];
    int b = blockIdx.x, t = threadIdx.x;

    // ---- in-block scan of all 784 bucket counts (4 per thread, 196 threads)
    int l0 = 0, l1 = 0, l2 = 0, l3 = 0;
    if (t < 196) {
        l0 = min(gcursor[(t * 4 + 0) * CUR_PAD], BCAP);
        l1 = min(gcursor[(t * 4 + 1) * CUR_PAD], BCAP);
        l2 = min(gcursor[(t * 4 + 2) * CUR_PAD], BCAP);
        l3 = min(gcursor[(t * 4 + 3) * CUR_PAD], BCAP);
    }
    int part = l0 + l1 + l2 + l3;
    s[t] = part;
    __syncthreads();
    for (int off = 1; off < 256; off <<= 1) {
        int a = (t >= off) ? s[t - off] : 0;
        __syncthreads();
        s[t] += a;
        __syncthreads();
    }
    if (t < 196) {
        int ex = s[t] - part;
        bb[t * 4 + 0] = ex;
        bb[t * 4 + 1] = ex + l0;
        bb[t * 4 + 2] = ex + l0 + l1;
        bb[t * 4 + 3] = ex + l0 + l1 + l2;
    }
    __syncthreads();
    int gbase = bb[b];
    int n = min(gcursor[b * CUR_PAD], BCAP);
    if (b == 0 && t == 0) rowptr[N_NODES] = s[255];

    // ---- per-row histogram within bucket
    const unsigned int* sb = sortbuf + (size_t)b * BCAP;
    if (t < ROWS_PB) cnt[t] = 0;
    __syncthreads();
    for (int i = t; i < n; i += 256) atomicAdd(&cnt[sb[i] >> 17], 1);
    __syncthreads();
    int c0 = (t < ROWS_PB) ? cnt[t] : 0;
    s[t] = c0;
    __syncthreads();
    for (int off = 1; off < 256; off <<= 1) {
        int a = (t >= off) ? s[t - off] : 0;
        __syncthreads();
        s[t] += a;
        __syncthreads();
    }
    if (t < ROWS_PB) {
        int ex = s[t] - c0;
        rstart[t] = ex;
        int g = b * ROWS_PB + t;
        if (g < N_NODES) {
            rowptr[g] = gbase + ex;
            dinv[g] = rsqrtf((float)(c0 + 1));   // +1 self-loop
        }
    }
    __syncthreads();
    if (t < ROWS_PB) cnt[t] = 0;  // reuse as cursor
    __syncthreads();
    for (int i = t; i < n; i += 256) {
        unsigned int v = sb[i];
        int lr = v >> 17;
        int pos = atomicAdd(&cnt[lr], 1);
        colv[gbase + rstart[lr] + pos] = (int)(v & 0x1FFFFu);
    }
}

// ---- GEMM1: Hs = (x @ W1) * dinv, 64 rows x 4 wave-uniform K-chunks/block ----
#define GROWS 64
#define RPAD 17

__global__ __launch_bounds__(256) void k_gemm1(const float* __restrict__ x,
                                               const float* __restrict__ W1,
                                               const float* __restrict__ dinv,
                                               float* __restrict__ Hs) {
    __shared__ float red[4 * GROWS * RPAD];   // 17.4 KB
    int t = threadIdx.x;
    // wave-uniform K-chunk id: readfirstlane forces SGPR -> W1 reads stay s_load
    int kc = __builtin_amdgcn_readfirstlane(t >> 6);
    int rl = t & 63;
    int row = blockIdx.x * GROWS + rl;

    float acc[HID];
#pragma unroll
    for (int f = 0; f < HID; ++f) acc[f] = 0.0f;

    if (row < N_NODES) {
        const float* xp = x + (size_t)row * F_IN + kc * 128;
        const float* wp = W1 + kc * 128 * HID;
        float4 a0 = *reinterpret_cast<const float4*>(xp);
        float4 a1 = *reinterpret_cast<const float4*>(xp + 4);
        float4 a2 = *reinterpret_cast<const float4*>(xp + 8);
        float4 a3 = *reinterpret_cast<const float4*>(xp + 12);
        for (int k = 0; k < 128; k += 16) {
            float4 n0, n1, n2, n3;
            if (k + 16 < 128) {
                n0 = *reinterpret_cast<const float4*>(xp + k + 16);
                n1 = *reinterpret_cast<const float4*>(xp + k + 20);
                n2 = *reinterpret_cast<const float4*>(xp + k + 24);
                n3 = *reinterpret_cast<const float4*>(xp + k + 28);
            } else {
                n0 = a0; n1 = a1; n2 = a2; n3 = a3;
            }
            float xs[16] = {a0.x, a0.y, a0.z, a0.w, a1.x, a1.y, a1.z, a1.w,
                            a2.x, a2.y, a2.z, a2.w, a3.x, a3.y, a3.z, a3.w};
#pragma unroll
            for (int kk = 0; kk < 16; ++kk) {
                float xv = xs[kk];
#pragma unroll
                for (int f = 0; f < HID; ++f)
                    acc[f] = fmaf(xv, wp[(k + kk) * HID + f], acc[f]);  // s_load
            }
            a0 = n0; a1 = n1; a2 = n2; a3 = n3;
        }
    }
    int base = (kc * GROWS + rl) * RPAD;
#pragma unroll
    for (int f = 0; f < HID; ++f) red[base + f] = acc[f];
    __syncthreads();
#pragma unroll
    for (int p = 0; p < 4; ++p) {
        int o = p * 256 + t;                  // 0..1023 = 64 rows x 16 f
        int r = o >> 4, f = o & 15;
        int rg = blockIdx.x * GROWS + r;
        if (rg < N_NODES) {
            float s = red[(0 * GROWS + r) * RPAD + f] + red[(1 * GROWS + r) * RPAD + f] +
                      red[(2 * GROWS + r) * RPAD + f] + red[(3 * GROWS + r) * RPAD + f];
            Hs[(size_t)rg * HID + f] = s * dinv[rg];
        }
    }
}

// -- agg1: wave/node pull, float4 gathers, scalar-hoisted row meta ------------
__global__ __launch_bounds__(256) void k_agg1(const int* __restrict__ rowptr,
                                              const int* __restrict__ colv,
                                              const float* __restrict__ dinv,
                                              const float* __restrict__ Hs,
                                              const float* __restrict__ b1,
                                              float* __restrict__ h1s) {
    int wid = __builtin_amdgcn_readfirstlane((blockIdx.x * 256 + threadIdx.x) >> 6);
    if (wid >= N_NODES) return;
    int lane = threadIdx.x & 63;
    int f4 = lane & 3, sub = lane >> 2;
    int beg = rowptr[wid], end = rowptr[wid + 1];   // s_load (wid scalar)
    float dr = dinv[wid];                            // s_load
    float4 acc = make_float4(0.f, 0.f, 0.f, 0.f);
    for (int j = beg + sub; j < end; j += 16) {
        int c = colv[j];
        float4 hv = *reinterpret_cast<const float4*>(Hs + (size_t)c * HID + f4 * 4);
        acc.x += hv.x; acc.y += hv.y; acc.z += hv.z; acc.w += hv.w;
    }
#pragma unroll
    for (int d = 4; d < 64; d <<= 1) {
        acc.x += __shfl_xor(acc.x, d);
        acc.y += __shfl_xor(acc.y, d);
        acc.z += __shfl_xor(acc.z, d);
        acc.w += __shfl_xor(acc.w, d);
    }
    if (sub == 0) {
        float4 self = *reinterpret_cast<const float4*>(Hs + (size_t)wid * HID + f4 * 4);
        float4 bb = *reinterpret_cast<const float4*>(b1 + f4 * 4);
        float4 o;
        o.x = fmaxf((acc.x + self.x) * dr + bb.x, 0.f) * dr;
        o.y = fmaxf((acc.y + self.y) * dr + bb.y, 0.f) * dr;
        o.z = fmaxf((acc.z + self.z) * dr + bb.z, 0.f) * dr;
        o.w = fmaxf((acc.w + self.w) * dr + bb.w, 0.f) * dr;
        *reinterpret_cast<float4*>(h1s + (size_t)wid * HID + f4 * 4) = o;
    }
}

// -- agg2: wave/node pull of h1s (float4), fused 16x40 GEMM + bias -> out -----
__global__ __launch_bounds__(256) void k_agg2(const int* __restrict__ rowptr,
                                              const int* __restrict__ colv,
                                              const float* __restrict__ dinv,
                                              const float* __restrict__ h1s,
                                              const float* __restrict__ W2,
                                              const float* __restrict__ b2,
                                              float* __restrict__ out) {
    int wid = __builtin_amdgcn_readfirstlane((blockIdx.x * 256 + threadIdx.x) >> 6);
    if (wid >= N_NODES) return;
    int lane = threadIdx.x & 63;
    int f4 = lane & 3, sub = lane >> 2;
    int beg = rowptr[wid], end = rowptr[wid + 1];   // s_load
    float dr = dinv[wid];                            // s_load
    float4 acc = make_float4(0.f, 0.f, 0.f, 0.f);
    for (int j = beg + sub; j < end; j += 16) {
        int c = colv[j];
        float4 hv = *reinterpret_cast<const float4*>(h1s + (size_t)c * HID + f4 * 4);
        acc.x += hv.x; acc.y += hv.y; acc.z += hv.z; acc.w += hv.w;
    }
#pragma unroll
    for (int d = 4; d < 64; d <<= 1) {
        acc.x += __shfl_xor(acc.x, d);
        acc.y += __shfl_xor(acc.y, d);
        acc.z += __shfl_xor(acc.z, d);
        acc.w += __shfl_xor(acc.w, d);
    }
    float4 self = *reinterpret_cast<const float4*>(h1s + (size_t)wid * HID + f4 * 4);
    float4 w4;
    w4.x = (acc.x + self.x) * dr;
    w4.y = (acc.y + self.y) * dr;
    w4.z = (acc.z + self.z) * dr;
    w4.w = (acc.w + self.w) * dr;
    if (lane < F_OUT) {
        float o = b2[lane];
#pragma unroll
        for (int k = 0; k < HID; ++k) {
            float comp = (k & 3) == 0 ? w4.x : (k & 3) == 1 ? w4.y
                        : (k & 3) == 2 ? w4.z : w4.w;
            float wk = __shfl(comp, k >> 2);   // lane k>>2 has f4 == k>>2
            o = fmaf(wk, W2[k * F_OUT + lane], o);
        }
        out[(size_t)wid * F_OUT + lane] = o;
    }
}

// ---------------- launch ----------------
extern "C" void kernel_launch(void* const* d_in, const int* in_sizes, int n_in,
                              void* d_out, int out_size, void* d_ws, size_t ws_size,
                              hipStream_t stream) {
    const float* x  = (const float*)d_in[0];
    const int* ei   = (const int*)d_in[1];      // int32 [2][E]
    const float* W1 = (const float*)d_in[2];
    const float* b1 = (const float*)d_in[3];
    const float* W2 = (const float*)d_in[4];
    const float* b2 = (const float*)d_in[5];
    float* out = (float*)d_out;
    const int E = in_sizes[1] / 2;

    // ws layout (4B units, 64B-aligned sections)
    int* gcursor          = (int*)d_ws;                      // 784*16 = 12544
    int* rowptr           = gcursor + 12544;                 // 100001 -> pad
    float* dinv           = (float*)(rowptr + 100016);       // 100000
    int* colv             = (int*)(dinv + 100000);           // 3,200,000
    unsigned int* sortbuf = (unsigned int*)(colv + 3200000); // 784*4608 = 3,612,672
    float* Hs             = (float*)sortbuf;                 // alias: dead after k_build
    float* h1s            = (float*)(sortbuf + 3612672);     // N*16
    // total ~34.6 MB

    const int nbW = (N_NODES * 64 + 255) / 256;    // 25000 (wave per node)
    const int nbG = (N_NODES + GROWS - 1) / GROWS; // 1563

    k_zero<<<(NB * CUR_PAD + 255) / 256, 256, 0, stream>>>(gcursor);
    k_part1<<<1024, 256, 0, stream>>>(ei, E, gcursor, sortbuf);
    k_build<<<NB, 256, 0, stream>>>(sortbuf, gcursor, rowptr, dinv, colv);

    k_gemm1<<<nbG, 256, 0, stream>>>(x, W1, dinv, Hs);

    k_agg1<<<nbW, 256, 0, stream>>>(rowptr, colv, dinv, Hs, b1, h1s);
    k_agg2<<<nbW, 256, 0, stream>>>(rowptr, colv, dinv, h1s, W2, b2, out);
}